// Round 5
// baseline (76431.201 us; speedup 1.0000x reference)
//
#include <hip/hip_runtime.h>
#include <stdint.h>

typedef unsigned short u16;
typedef unsigned int   u32;

#define DEVINL __device__ __forceinline__

typedef __bf16 bf16x8 __attribute__((ext_vector_type(8)));

#define RSQRT512 0.044194173824159216f
#define LRELU_G  1.4142135623730951f

DEVINL u16 f2bf(float f) {           // RNE float->bf16 bits
  union { float f; u32 u; } v; v.f = f;
  u32 r = v.u + 0x7fffu + ((v.u >> 16) & 1u);
  return (u16)(r >> 16);
}
DEVINL float bf2f(u16 b) {
  union { u32 u; float f; } v; v.u = ((u32)b) << 16;
  return v.f;
}

// ---------------------------------------------------------------------------
// 1) styles: s_all[j][b][o] = ws[b,j,:]@A_j[o,:]/sqrt(512) + ab_j[o]; j==2 *= 1/sqrt(512)
// ---------------------------------------------------------------------------
__global__ __launch_bounds__(256)
void style_kernel(const float* __restrict__ wsin,
                  const float* __restrict__ a0w, const float* __restrict__ a0b,
                  const float* __restrict__ a1w, const float* __restrict__ a1b,
                  const float* __restrict__ atw, const float* __restrict__ atb,
                  float* __restrict__ s_all)
{
  int wid = threadIdx.x >> 6, lane = threadIdx.x & 63;
  int idx = blockIdx.x * 4 + wid;            // [0, 3*8*512)
  int j = idx >> 12;
  int b = (idx >> 9) & 7;
  int o = idx & 511;
  const float* A  = (j == 0) ? a0w : ((j == 1) ? a1w : atw);
  const float* Ab = (j == 0) ? a0b : ((j == 1) ? a1b : atb);
  const float* wv = wsin + (b * 3 + j) * 512;
  float p = 0.f;
  #pragma unroll
  for (int m = 0; m < 512; m += 64) p += wv[m + lane] * A[(size_t)o * 512 + m + lane];
  #pragma unroll
  for (int s = 32; s; s >>= 1) p += __shfl_xor(p, s, 64);
  if (lane == 0) {
    float v = p * RSQRT512 + Ab[o];
    if (j == 2) v *= RSQRT512;
    s_all[idx] = v;
  }
}

// ---------------------------------------------------------------------------
// 2) weight prep: modulate + demod, emit bf16 [b][o][tap*512 + i]
//    FLIP=1: tap index is (2-ky)*3+(2-kx)   (conv0's spatially-flipped kernel)
// ---------------------------------------------------------------------------
template <int FLIP>
__global__ __launch_bounds__(256)
void wprep_kernel(const float* __restrict__ w, const float* __restrict__ s_j,
                  u16* __restrict__ wg)
{
  int b = blockIdx.x >> 9;
  int o = blockIdx.x & 511;
  __shared__ float s_sh[512];
  __shared__ float red[4];
  int t = threadIdx.x;
  s_sh[t]       = s_j[b * 512 + t];
  s_sh[t + 256] = s_j[b * 512 + t + 256];
  __syncthreads();
  float wv[2][9];
  float ssq = 0.f;
  #pragma unroll
  for (int hh = 0; hh < 2; ++hh) {
    int i = t + hh * 256;
    float si = s_sh[i];
    const float* wp = w + ((size_t)o * 512 + i) * 9;
    #pragma unroll
    for (int k = 0; k < 9; ++k) { float v = wp[k] * si; wv[hh][k] = v; ssq += v * v; }
  }
  #pragma unroll
  for (int s = 32; s; s >>= 1) ssq += __shfl_xor(ssq, s, 64);
  if ((t & 63) == 0) red[t >> 6] = ssq;
  __syncthreads();
  float d = red[0] + red[1] + red[2] + red[3];
  d = 1.0f / sqrtf(d + 1e-8f);
  u16* out = wg + ((size_t)(b * 512 + o)) * 4608;
  #pragma unroll
  for (int hh = 0; hh < 2; ++hh) {
    int i = t + hh * 256;
    #pragma unroll
    for (int ky = 0; ky < 3; ++ky)
      #pragma unroll
      for (int kx = 0; kx < 3; ++kx) {
        int tap = FLIP ? ((2 - ky) * 3 + (2 - kx)) : (ky * 3 + kx);
        out[tap * 512 + i] = f2bf(wv[hh][ky * 3 + kx] * d);
      }
  }
}

// ---------------------------------------------------------------------------
// 3) x (NCHW f32 32x32) -> xt (NHWC f32 [b][y][x][512]) via LDS transpose
// ---------------------------------------------------------------------------
__global__ __launch_bounds__(256)
void transpose_x(const float* __restrict__ x, float* __restrict__ xt)
{
  int b = blockIdx.x >> 5, y = blockIdx.x & 31;
  __shared__ __align__(16) float lds[32][260];
  int t = threadIdx.x;
  #pragma unroll 1
  for (int half = 0; half < 2; ++half) {
    for (int idx = t; idx < 8192; idx += 256) {
      int xq = idx & 31, i = idx >> 5;
      lds[xq][i] = x[(((size_t)(b * 512 + half * 256 + i)) << 10) + (y << 5) + xq];
    }
    __syncthreads();
    for (int idx = t; idx < 2048; idx += 256) {
      int xq = idx >> 6, i4 = idx & 63;
      float4 v = *(const float4*)&lds[xq][i4 * 4];
      *(float4*)&xt[((size_t)((b * 32 + y) * 32 + xq) << 9) + half * 256 + i4 * 4] = v;
    }
    __syncthreads();
  }
}

// ---------------------------------------------------------------------------
// 4) blur-upsample: xt f32 [b][32][32][512] -> xb bf16 [b][66][66][512]
//    upfirdn2d(up=2, pad 3/2, gain 4) per-dim taps (.75/.25)
// ---------------------------------------------------------------------------
__global__ __launch_bounds__(256)
void upblur_kernel(const float* __restrict__ xt, u16* __restrict__ xb)
{
  int b = blockIdx.x / 66, p = blockIdx.x - b * 66;
  int t = threadIdx.x;
  int ch = t << 1;
  int m0, m1; float wy0, wy1;
  if ((p & 1) == 0) { m0 = (p >> 1) - 1; wy0 = 0.75f; m1 = p >> 1;       wy1 = 0.25f; }
  else              { m0 = (p - 3) >> 1; wy0 = 0.25f; m1 = (p - 1) >> 1; wy1 = 0.75f; }
  bool vm0 = (unsigned)m0 < 32u, vm1 = (unsigned)m1 < 32u;
  const float* base = xt + (size_t)b * 524288;            // b*32*32*512
  u16* ob = xb + ((size_t)(b * 66 + p)) * 66 * 512;
  for (int q = 0; q < 66; ++q) {
    int n0, n1; float wx0, wx1;
    if ((q & 1) == 0) { n0 = (q >> 1) - 1; wx0 = 0.75f; n1 = q >> 1;       wx1 = 0.25f; }
    else              { n0 = (q - 3) >> 1; wx0 = 0.25f; n1 = (q - 1) >> 1; wx1 = 0.75f; }
    bool vn0 = (unsigned)n0 < 32u, vn1 = (unsigned)n1 < 32u;
    float a0 = 0.f, a1 = 0.f;
    if (vm0 & vn0) { float2 u = *(const float2*)(base + (((size_t)m0 * 32 + n0) << 9) + ch);
                     float w = wy0 * wx0; a0 += w * u.x; a1 += w * u.y; }
    if (vm0 & vn1) { float2 u = *(const float2*)(base + (((size_t)m0 * 32 + n1) << 9) + ch);
                     float w = wy0 * wx1; a0 += w * u.x; a1 += w * u.y; }
    if (vm1 & vn0) { float2 u = *(const float2*)(base + (((size_t)m1 * 32 + n0) << 9) + ch);
                     float w = wy1 * wx0; a0 += w * u.x; a1 += w * u.y; }
    if (vm1 & vn1) { float2 u = *(const float2*)(base + (((size_t)m1 * 32 + n1) << 9) + ch);
                     float w = wy1 * wx1; a0 += w * u.x; a1 += w * u.y; }
    u32 outv = (u32)f2bf(a0) | ((u32)f2bf(a1) << 16);
    *(u32*)(ob + (q << 9) + ch) = outv;
  }
}

// ---------------------------------------------------------------------------
// 5) DIRECT conv (bisection round): plain f32 VALU, no MFMA, no X-LDS.
//    Consumes identical wg/xb/hp tensors and identical epilogues as the
//    MFMA path. One block = one (b, o); 256 threads x 16 pixels.
//    EPI=0 (conv0): out -> hp NHWC bf16 (padded, +1 ring offset)
//    EPI=1 (conv1): out -> h NCHW f32 (d_out)
// ---------------------------------------------------------------------------
template <int EPI>
__global__ __launch_bounds__(256)
void direct_conv(const u16* __restrict__ xin,   // [b][66][66][512] bf16
                 const u16* __restrict__ wg,    // [b][512][4608]   bf16
                 const float* __restrict__ noise,  // [64*64]
                 const float* __restrict__ nsp,    // scalar
                 const float* __restrict__ bias,   // [512]
                 u16* __restrict__ hpOut,          // EPI=0 dest
                 float* __restrict__ hOut)         // EPI=1 dest
{
  int b = blockIdx.x >> 9;
  int o = blockIdx.x & 511;
  __shared__ float wl[4608];
  int t = threadIdx.x;
  const u16* wrow = wg + ((size_t)(b * 512 + o)) * 4608;
  for (int i = t; i < 4608; i += 256) wl[i] = bf2f(wrow[i]);
  __syncthreads();
  const u16* xbase = xin + (size_t)b * (66 * 66 * 512);
  float ns = nsp[0], bo = bias[o];
  #pragma unroll 1
  for (int i = 0; i < 16; ++i) {
    int p = t + (i << 8);
    int y = p >> 6, x = p & 63;
    float a = 0.f;
    #pragma unroll 1
    for (int tap = 0; tap < 9; ++tap) {
      int dy = (tap * 171) >> 9;    // tap/3
      int dx = tap - dy * 3;
      const u16* src = xbase + (((size_t)(y + dy) * 66 + (x + dx)) << 9);
      const float* wt_ = &wl[tap << 9];
      #pragma unroll 4
      for (int c8 = 0; c8 < 64; ++c8) {
        bf16x8 v = *(const bf16x8*)(src + (c8 << 3));
        #pragma unroll
        for (int j = 0; j < 8; ++j) a = fmaf((float)v[j], wt_[(c8 << 3) + j], a);
      }
    }
    float val = a + noise[p] * ns + bo;
    val = (val >= 0.f ? val : 0.2f * val) * LRELU_G;
    val = fminf(fmaxf(val, -256.f), 256.f);
    if constexpr (EPI == 0) {
      hpOut[((size_t)b * 4356 + (size_t)(y + 1) * 66 + (x + 1)) * 512 + o] = f2bf(val);
    } else {
      hOut[((size_t)(b * 512 + o) << 12) + p] = val;
    }
  }
}

// ---------------------------------------------------------------------------
// 6) toRGB + img skip: out2 = img_up + clip(sum_i h*st*wt + bt, +-256)
// ---------------------------------------------------------------------------
__global__ __launch_bounds__(256)
void torgb_kernel(const float* __restrict__ h, const float* __restrict__ s_all,
                  const float* __restrict__ wt, const float* __restrict__ bt,
                  const float* __restrict__ img, float* __restrict__ out2)
{
  int b = blockIdx.x >> 4;
  int y = ((blockIdx.x & 15) << 2) + (threadIdx.x >> 6);
  int x = threadIdx.x & 63;
  __shared__ float stw[3][512];
  const float* st = s_all + 2 * 4096 + b * 512;
  for (int i = threadIdx.x; i < 512; i += 256) {
    float s = st[i];
    stw[0][i] = s * wt[i];
    stw[1][i] = s * wt[512 + i];
    stw[2][i] = s * wt[1024 + i];
  }
  __syncthreads();
  const float* hp = h + ((size_t)b * 512 << 12) + (y << 6) + x;
  float a0 = 0.f, a1 = 0.f, a2 = 0.f;
  #pragma unroll 8
  for (int i = 0; i < 512; ++i) {
    float v = hp[(size_t)i << 12];
    a0 += v * stw[0][i]; a1 += v * stw[1][i]; a2 += v * stw[2][i];
  }
  float accs[3] = {a0, a1, a2};
  // img upfirdn (up=2, pad 2/1, gain 4): per-dim taps
  int my0, my1; float wy0, wy1;
  if ((y & 1) == 0) { my0 = (y >> 1) - 1; wy0 = 0.25f; my1 = y >> 1;       wy1 = 0.75f; }
  else              { my0 = y >> 1;       wy0 = 0.75f; my1 = (y >> 1) + 1; wy1 = 0.25f; }
  int mx0, mx1; float wx0, wx1;
  if ((x & 1) == 0) { mx0 = (x >> 1) - 1; wx0 = 0.25f; mx1 = x >> 1;       wx1 = 0.75f; }
  else              { mx0 = x >> 1;       wx0 = 0.75f; mx1 = (x >> 1) + 1; wx1 = 0.25f; }
  bool vy0 = (unsigned)my0 < 32u, vy1 = (unsigned)my1 < 32u;
  bool vx0 = (unsigned)mx0 < 32u, vx1 = (unsigned)mx1 < 32u;
  #pragma unroll
  for (int o = 0; o < 3; ++o) {
    float yv = fminf(fmaxf(accs[o] + bt[o], -256.f), 256.f);
    const float* ib = img + ((size_t)(b * 3 + o) << 10);
    float iu = 0.f;
    if (vy0 & vx0) iu += wy0 * wx0 * ib[(my0 << 5) + mx0];
    if (vy0 & vx1) iu += wy0 * wx1 * ib[(my0 << 5) + mx1];
    if (vy1 & vx0) iu += wy1 * wx0 * ib[(my1 << 5) + mx0];
    if (vy1 & vx1) iu += wy1 * wx1 * ib[(my1 << 5) + mx1];
    out2[((size_t)(b * 3 + o) << 12) + (y << 6) + x] = iu + yv;
  }
}

// ---------------------------------------------------------------------------
extern "C" void kernel_launch(void* const* d_in, const int* in_sizes, int n_in,
                              void* d_out, int out_size, void* d_ws, size_t ws_size,
                              hipStream_t stream) {
  (void)in_sizes; (void)n_in; (void)out_size; (void)ws_size;
  const float* x   = (const float*)d_in[0];
  const float* img = (const float*)d_in[1];
  const float* ws_ = (const float*)d_in[2];
  const float* a0w = (const float*)d_in[3];
  const float* a0b = (const float*)d_in[4];
  const float* w0  = (const float*)d_in[5];
  const float* b0  = (const float*)d_in[6];
  const float* ns0 = (const float*)d_in[7];
  const float* nc0 = (const float*)d_in[8];
  const float* a1w = (const float*)d_in[9];
  const float* a1b = (const float*)d_in[10];
  const float* w1  = (const float*)d_in[11];
  const float* b1  = (const float*)d_in[12];
  const float* ns1 = (const float*)d_in[13];
  const float* nc1 = (const float*)d_in[14];
  const float* atw = (const float*)d_in[15];
  const float* atb = (const float*)d_in[16];
  const float* wt  = (const float*)d_in[17];
  const float* bt  = (const float*)d_in[18];

  // workspace carve (total ~146.9 MB), all offsets 16B-aligned
  char* wsp = (char*)d_ws;
  float* s_all = (float*)wsp;                                   //      49,152 B
  u16* wg0 = (u16*)(wsp + 49152);                               //  37,748,736 B
  u16* wg1 = (u16*)(wsp + 49152 + 37748736ull);                 //  37,748,736 B
  u16* xb  = (u16*)(wsp + 49152 + 2ull * 37748736);             //  35,684,352 B
  u16* hp  = (u16*)(wsp + 49152 + 2ull * 37748736 + 35684352);  //  35,684,352 B
  float* xtf = (float*)hp;   // xt f32 (16,777,216 B) aliases hp; dead before memset

  float* h_out = (float*)d_out;
  float* out2  = (float*)d_out + 16777216;

  style_kernel<<<3072, 256, 0, stream>>>(ws_, a0w, a0b, a1w, a1b, atw, atb, s_all);
  wprep_kernel<1><<<4096, 256, 0, stream>>>(w0, s_all, wg0);           // conv0: flipped
  wprep_kernel<0><<<4096, 256, 0, stream>>>(w1, s_all + 4096, wg1);    // conv1
  transpose_x<<<256, 256, 0, stream>>>(x, xtf);
  upblur_kernel<<<528, 256, 0, stream>>>(xtf, xb);
  hipMemsetAsync(hp, 0, 35684352, stream);  // zero padded ring for conv1 input (xtf now dead)
  direct_conv<0><<<4096, 256, 0, stream>>>(xb, wg0, nc0, ns0, b0, hp, nullptr);
  direct_conv<1><<<4096, 256, 0, stream>>>(hp, wg1, nc1, ns1, b1, nullptr, h_out);
  torgb_kernel<<<128, 256, 0, stream>>>(h_out, s_all, wt, bt, img, out2);
}

// Round 6
// 1175.307 us; speedup vs baseline: 65.0309x; 65.0309x over previous
//
#include <hip/hip_runtime.h>
#include <stdint.h>

typedef unsigned short u16;
typedef unsigned int   u32;

#define DEVINL __device__ __forceinline__

typedef __bf16 bf16x8 __attribute__((ext_vector_type(8)));
typedef float  f32x4  __attribute__((ext_vector_type(4)));

#define RSQRT512 0.044194173824159216f
#define LRELU_G  1.4142135623730951f

DEVINL u16 f2bf(float f) {           // RNE float->bf16 bits
  union { float f; u32 u; } v; v.f = f;
  u32 r = v.u + 0x7fffu + ((v.u >> 16) & 1u);
  return (u16)(r >> 16);
}
DEVINL float bf2f(u16 b) {
  union { u32 u; float f; } v; v.u = ((u32)b) << 16;
  return v.f;
}

// ---------------------------------------------------------------------------
// 1) styles: s_all[j][b][o] = ws[b,j,:]@A_j[o,:]/sqrt(512) + ab_j[o]; j==2 *= 1/sqrt(512)
// ---------------------------------------------------------------------------
__global__ __launch_bounds__(256)
void style_kernel(const float* __restrict__ wsin,
                  const float* __restrict__ a0w, const float* __restrict__ a0b,
                  const float* __restrict__ a1w, const float* __restrict__ a1b,
                  const float* __restrict__ atw, const float* __restrict__ atb,
                  float* __restrict__ s_all)
{
  int wid = threadIdx.x >> 6, lane = threadIdx.x & 63;
  int idx = blockIdx.x * 4 + wid;            // [0, 3*8*512)
  int j = idx >> 12;
  int b = (idx >> 9) & 7;
  int o = idx & 511;
  const float* A  = (j == 0) ? a0w : ((j == 1) ? a1w : atw);
  const float* Ab = (j == 0) ? a0b : ((j == 1) ? a1b : atb);
  const float* wv = wsin + (b * 3 + j) * 512;
  float p = 0.f;
  #pragma unroll
  for (int m = 0; m < 512; m += 64) p += wv[m + lane] * A[(size_t)o * 512 + m + lane];
  #pragma unroll
  for (int s = 32; s; s >>= 1) p += __shfl_xor(p, s, 64);
  if (lane == 0) {
    float v = p * RSQRT512 + Ab[o];
    if (j == 2) v *= RSQRT512;
    s_all[idx] = v;
  }
}

// ---------------------------------------------------------------------------
// 2) weight prep: modulate + demod, emit bf16 [b][o][tap*512 + i]
//    FLIP=1: tap index is (2-ky)*3+(2-kx)   (conv0's spatially-flipped kernel)
// ---------------------------------------------------------------------------
template <int FLIP>
__global__ __launch_bounds__(256)
void wprep_kernel(const float* __restrict__ w, const float* __restrict__ s_j,
                  u16* __restrict__ wg)
{
  int b = blockIdx.x >> 9;
  int o = blockIdx.x & 511;
  __shared__ float s_sh[512];
  __shared__ float red[4];
  int t = threadIdx.x;
  s_sh[t]       = s_j[b * 512 + t];
  s_sh[t + 256] = s_j[b * 512 + t + 256];
  __syncthreads();
  float wv[2][9];
  float ssq = 0.f;
  #pragma unroll
  for (int hh = 0; hh < 2; ++hh) {
    int i = t + hh * 256;
    float si = s_sh[i];
    const float* wp = w + ((size_t)o * 512 + i) * 9;
    #pragma unroll
    for (int k = 0; k < 9; ++k) { float v = wp[k] * si; wv[hh][k] = v; ssq += v * v; }
  }
  #pragma unroll
  for (int s = 32; s; s >>= 1) ssq += __shfl_xor(ssq, s, 64);
  if ((t & 63) == 0) red[t >> 6] = ssq;
  __syncthreads();
  float d = red[0] + red[1] + red[2] + red[3];
  d = 1.0f / sqrtf(d + 1e-8f);
  u16* out = wg + ((size_t)(b * 512 + o)) * 4608;
  #pragma unroll
  for (int hh = 0; hh < 2; ++hh) {
    int i = t + hh * 256;
    #pragma unroll
    for (int ky = 0; ky < 3; ++ky)
      #pragma unroll
      for (int kx = 0; kx < 3; ++kx) {
        int tap = FLIP ? ((2 - ky) * 3 + (2 - kx)) : (ky * 3 + kx);
        out[tap * 512 + i] = f2bf(wv[hh][ky * 3 + kx] * d);
      }
  }
}

// ---------------------------------------------------------------------------
// 3) x (NCHW f32 32x32) -> xt (NHWC f32 [b][y][x][512]) via LDS transpose
// ---------------------------------------------------------------------------
__global__ __launch_bounds__(256)
void transpose_x(const float* __restrict__ x, float* __restrict__ xt)
{
  int b = blockIdx.x >> 5, y = blockIdx.x & 31;
  __shared__ __align__(16) float lds[32][260];
  int t = threadIdx.x;
  #pragma unroll 1
  for (int half = 0; half < 2; ++half) {
    for (int idx = t; idx < 8192; idx += 256) {
      int xq = idx & 31, i = idx >> 5;
      lds[xq][i] = x[(((size_t)(b * 512 + half * 256 + i)) << 10) + (y << 5) + xq];
    }
    __syncthreads();
    for (int idx = t; idx < 2048; idx += 256) {
      int xq = idx >> 6, i4 = idx & 63;
      float4 v = *(const float4*)&lds[xq][i4 * 4];
      *(float4*)&xt[((size_t)((b * 32 + y) * 32 + xq) << 9) + half * 256 + i4 * 4] = v;
    }
    __syncthreads();
  }
}

// ---------------------------------------------------------------------------
// 4) blur-upsample: xt f32 [b][32][32][512] -> xb bf16 [b][66][66][512]
//    upfirdn2d(up=2, pad 3/2, gain 4) per-dim taps (.75/.25)
// ---------------------------------------------------------------------------
__global__ __launch_bounds__(256)
void upblur_kernel(const float* __restrict__ xt, u16* __restrict__ xb)
{
  int b = blockIdx.x / 66, p = blockIdx.x - b * 66;
  int t = threadIdx.x;
  int ch = t << 1;
  int m0, m1; float wy0, wy1;
  if ((p & 1) == 0) { m0 = (p >> 1) - 1; wy0 = 0.75f; m1 = p >> 1;       wy1 = 0.25f; }
  else              { m0 = (p - 3) >> 1; wy0 = 0.25f; m1 = (p - 1) >> 1; wy1 = 0.75f; }
  bool vm0 = (unsigned)m0 < 32u, vm1 = (unsigned)m1 < 32u;
  const float* base = xt + (size_t)b * 524288;            // b*32*32*512
  u16* ob = xb + ((size_t)(b * 66 + p)) * 66 * 512;
  for (int q = 0; q < 66; ++q) {
    int n0, n1; float wx0, wx1;
    if ((q & 1) == 0) { n0 = (q >> 1) - 1; wx0 = 0.75f; n1 = q >> 1;       wx1 = 0.25f; }
    else              { n0 = (q - 3) >> 1; wx0 = 0.25f; n1 = (q - 1) >> 1; wx1 = 0.75f; }
    bool vn0 = (unsigned)n0 < 32u, vn1 = (unsigned)n1 < 32u;
    float a0 = 0.f, a1 = 0.f;
    if (vm0 & vn0) { float2 u = *(const float2*)(base + (((size_t)m0 * 32 + n0) << 9) + ch);
                     float w = wy0 * wx0; a0 += w * u.x; a1 += w * u.y; }
    if (vm0 & vn1) { float2 u = *(const float2*)(base + (((size_t)m0 * 32 + n1) << 9) + ch);
                     float w = wy0 * wx1; a0 += w * u.x; a1 += w * u.y; }
    if (vm1 & vn0) { float2 u = *(const float2*)(base + (((size_t)m1 * 32 + n0) << 9) + ch);
                     float w = wy1 * wx0; a0 += w * u.x; a1 += w * u.y; }
    if (vm1 & vn1) { float2 u = *(const float2*)(base + (((size_t)m1 * 32 + n1) << 9) + ch);
                     float w = wy1 * wx1; a0 += w * u.x; a1 += w * u.y; }
    u32 outv = (u32)f2bf(a0) | ((u32)f2bf(a1) << 16);
    *(u32*)(ob + (q << 9) + ch) = outv;
  }
}

// ---------------------------------------------------------------------------
// 5) no-LDS wave-tile MFMA conv (bisection: fragments straight from global).
//    One wave = one (b, o-group of 64, output row y); computes 64o x 64px.
//    mfma_f32_16x16x32_bf16; lane(gq=lane>>4, r=lane&15):
//      frag row = f*16+r, k = tap*512 + c0 + gq*8 + [0..8)
//    EPI=0 (conv0): A=pixels -> D[px][o], out hp NHWC bf16 (padded ring +1)
//    EPI=1 (conv1): A=weights -> D[o][px], out h NCHW f32 (d_out)
// ---------------------------------------------------------------------------
template <int EPI>
__global__ __launch_bounds__(64)
void mfma_conv(const u16* __restrict__ xin,   // [b][66][66][512] bf16
               const u16* __restrict__ wg,    // [b][512][4608]   bf16
               const float* __restrict__ noise,  // [64*64]
               const float* __restrict__ nsp,    // scalar
               const float* __restrict__ bias,   // [512]
               u16* __restrict__ hpOut,          // EPI=0 dest
               float* __restrict__ hOut)         // EPI=1 dest
{
  int blk = blockIdx.x;
  int b  = blk >> 9;
  int og = (blk >> 6) & 7;
  int y  = blk & 63;
  int o0 = og << 6;
  int lane = threadIdx.x;
  int gq = lane >> 4, r = lane & 15;

  f32x4 acc[4][4];
  #pragma unroll
  for (int i = 0; i < 4; ++i)
    #pragma unroll
    for (int j = 0; j < 4; ++j) acc[i][j] = (f32x4){0.f, 0.f, 0.f, 0.f};

  // per-lane bases (u16 units)
  const u16* wb = wg + ((size_t)(b * 512 + o0 + r)) * 4608 + gq * 8;
  const u16* xbl = xin + ((size_t)b * 4356 << 9) + ((size_t)r << 9) + gq * 8;

  #pragma unroll 1
  for (int tap = 0; tap < 9; ++tap) {
    int dy = (tap * 171) >> 9;       // tap/3 for tap in [0,9)
    int dx = tap - dy * 3;
    const u16* xrow = xbl + (((size_t)(y + dy) * 66 + dx) << 9);
    const u16* wtap = wb + tap * 512;
    #pragma unroll 2
    for (int c0 = 0; c0 < 512; c0 += 32) {
      bf16x8 wf[4], xf[4];
      #pragma unroll
      for (int f = 0; f < 4; ++f) {
        wf[f] = *(const bf16x8*)(wtap + f * 73728 + c0);   // (f*16)*4608
        xf[f] = *(const bf16x8*)(xrow + f * 8192 + c0);    // (f*16)*512
      }
      #pragma unroll
      for (int fa = 0; fa < 4; ++fa)
        #pragma unroll
        for (int fb = 0; fb < 4; ++fb) {
          if constexpr (EPI == 0)
            acc[fa][fb] = __builtin_amdgcn_mfma_f32_16x16x32_bf16(xf[fa], wf[fb], acc[fa][fb], 0, 0, 0);
          else
            acc[fa][fb] = __builtin_amdgcn_mfma_f32_16x16x32_bf16(wf[fa], xf[fb], acc[fa][fb], 0, 0, 0);
        }
    }
  }

  float ns = nsp[0];
  // C/D map (HW-verified): col = lane&15 (B-index), row = (lane>>4)*4 + v (A-index)
  if constexpr (EPI == 0) {
    // A = pixels: px_in_frag = gq*4+v ; B = weights: o_in_frag = r
    #pragma unroll
    for (int fa = 0; fa < 4; ++fa) {
      #pragma unroll
      for (int fb = 0; fb < 4; ++fb) {
        int oo = o0 + fb * 16 + r;
        float bo = bias[oo];
        #pragma unroll
        for (int v = 0; v < 4; ++v) {
          int x = fa * 16 + gq * 4 + v;
          int p = (y << 6) + x;
          float val = acc[fa][fb][v] + noise[p] * ns + bo;
          val = (val >= 0.f ? val : 0.2f * val) * LRELU_G;
          val = fminf(fmaxf(val, -256.f), 256.f);
          hpOut[((size_t)b * 4356 + (size_t)(y + 1) * 66 + (x + 1)) * 512 + oo] = f2bf(val);
        }
      }
    }
  } else {
    // A = weights: o_in_frag = gq*4+v ; B = pixels: px_in_frag = r
    #pragma unroll
    for (int fa = 0; fa < 4; ++fa) {
      #pragma unroll
      for (int fb = 0; fb < 4; ++fb) {
        int x = fb * 16 + r;
        int p = (y << 6) + x;
        float nv = noise[p] * ns;
        #pragma unroll
        for (int v = 0; v < 4; ++v) {
          int oo = o0 + fa * 16 + gq * 4 + v;
          float val = acc[fa][fb][v] + nv + bias[oo];
          val = (val >= 0.f ? val : 0.2f * val) * LRELU_G;
          val = fminf(fmaxf(val, -256.f), 256.f);
          hOut[((size_t)(b * 512 + oo) << 12) + p] = val;
        }
      }
    }
  }
}

// ---------------------------------------------------------------------------
// 6) toRGB + img skip: out2 = img_up + clip(sum_i h*st*wt + bt, +-256)
// ---------------------------------------------------------------------------
__global__ __launch_bounds__(256)
void torgb_kernel(const float* __restrict__ h, const float* __restrict__ s_all,
                  const float* __restrict__ wt, const float* __restrict__ bt,
                  const float* __restrict__ img, float* __restrict__ out2)
{
  int b = blockIdx.x >> 4;
  int y = ((blockIdx.x & 15) << 2) + (threadIdx.x >> 6);
  int x = threadIdx.x & 63;
  __shared__ float stw[3][512];
  const float* st = s_all + 2 * 4096 + b * 512;
  for (int i = threadIdx.x; i < 512; i += 256) {
    float s = st[i];
    stw[0][i] = s * wt[i];
    stw[1][i] = s * wt[512 + i];
    stw[2][i] = s * wt[1024 + i];
  }
  __syncthreads();
  const float* hp = h + ((size_t)b * 512 << 12) + (y << 6) + x;
  float a0 = 0.f, a1 = 0.f, a2 = 0.f;
  #pragma unroll 8
  for (int i = 0; i < 512; ++i) {
    float v = hp[(size_t)i << 12];
    a0 += v * stw[0][i]; a1 += v * stw[1][i]; a2 += v * stw[2][i];
  }
  float accs[3] = {a0, a1, a2};
  // img upfirdn (up=2, pad 2/1, gain 4): per-dim taps
  int my0, my1; float wy0, wy1;
  if ((y & 1) == 0) { my0 = (y >> 1) - 1; wy0 = 0.25f; my1 = y >> 1;       wy1 = 0.75f; }
  else              { my0 = y >> 1;       wy0 = 0.75f; my1 = (y >> 1) + 1; wy1 = 0.25f; }
  int mx0, mx1; float wx0, wx1;
  if ((x & 1) == 0) { mx0 = (x >> 1) - 1; wx0 = 0.25f; mx1 = x >> 1;       wx1 = 0.75f; }
  else              { mx0 = x >> 1;       wx0 = 0.75f; mx1 = (x >> 1) + 1; wx1 = 0.25f; }
  bool vy0 = (unsigned)my0 < 32u, vy1 = (unsigned)my1 < 32u;
  bool vx0 = (unsigned)mx0 < 32u, vx1 = (unsigned)mx1 < 32u;
  #pragma unroll
  for (int o = 0; o < 3; ++o) {
    float yv = fminf(fmaxf(accs[o] + bt[o], -256.f), 256.f);
    const float* ib = img + ((size_t)(b * 3 + o) << 10);
    float iu = 0.f;
    if (vy0 & vx0) iu += wy0 * wx0 * ib[(my0 << 5) + mx0];
    if (vy0 & vx1) iu += wy0 * wx1 * ib[(my0 << 5) + mx1];
    if (vy1 & vx0) iu += wy1 * wx0 * ib[(my1 << 5) + mx0];
    if (vy1 & vx1) iu += wy1 * wx1 * ib[(my1 << 5) + mx1];
    out2[((size_t)(b * 3 + o) << 12) + (y << 6) + x] = iu + yv;
  }
}

// ---------------------------------------------------------------------------
extern "C" void kernel_launch(void* const* d_in, const int* in_sizes, int n_in,
                              void* d_out, int out_size, void* d_ws, size_t ws_size,
                              hipStream_t stream) {
  (void)in_sizes; (void)n_in; (void)out_size; (void)ws_size;
  const float* x   = (const float*)d_in[0];
  const float* img = (const float*)d_in[1];
  const float* ws_ = (const float*)d_in[2];
  const float* a0w = (const float*)d_in[3];
  const float* a0b = (const float*)d_in[4];
  const float* w0  = (const float*)d_in[5];
  const float* b0  = (const float*)d_in[6];
  const float* ns0 = (const float*)d_in[7];
  const float* nc0 = (const float*)d_in[8];
  const float* a1w = (const float*)d_in[9];
  const float* a1b = (const float*)d_in[10];
  const float* w1  = (const float*)d_in[11];
  const float* b1  = (const float*)d_in[12];
  const float* ns1 = (const float*)d_in[13];
  const float* nc1 = (const float*)d_in[14];
  const float* atw = (const float*)d_in[15];
  const float* atb = (const float*)d_in[16];
  const float* wt  = (const float*)d_in[17];
  const float* bt  = (const float*)d_in[18];

  // workspace carve (total ~146.9 MB), all offsets 16B-aligned
  char* wsp = (char*)d_ws;
  float* s_all = (float*)wsp;                                   //      49,152 B
  u16* wg0 = (u16*)(wsp + 49152);                               //  37,748,736 B
  u16* wg1 = (u16*)(wsp + 49152 + 37748736ull);                 //  37,748,736 B
  u16* xb  = (u16*)(wsp + 49152 + 2ull * 37748736);             //  35,684,352 B
  u16* hp  = (u16*)(wsp + 49152 + 2ull * 37748736 + 35684352);  //  35,684,352 B
  float* xtf = (float*)hp;   // xt f32 (16,777,216 B) aliases hp; dead before memset

  float* h_out = (float*)d_out;
  float* out2  = (float*)d_out + 16777216;

  style_kernel<<<3072, 256, 0, stream>>>(ws_, a0w, a0b, a1w, a1b, atw, atb, s_all);
  wprep_kernel<1><<<4096, 256, 0, stream>>>(w0, s_all, wg0);           // conv0: flipped
  wprep_kernel<0><<<4096, 256, 0, stream>>>(w1, s_all + 4096, wg1);    // conv1
  transpose_x<<<256, 256, 0, stream>>>(x, xtf);
  upblur_kernel<<<528, 256, 0, stream>>>(xtf, xb);
  hipMemsetAsync(hp, 0, 35684352, stream);  // zero padded ring for conv1 input (xtf now dead)
  mfma_conv<0><<<4096, 64, 0, stream>>>(xb, wg0, nc0, ns0, b0, hp, nullptr);
  mfma_conv<1><<<4096, 64, 0, stream>>>(hp, wg1, nc1, ns1, b1, nullptr, h_out);
  torgb_kernel<<<128, 256, 0, stream>>>(h_out, s_all, wt, bt, img, out2);
}

// Round 7
// 520.149 us; speedup vs baseline: 146.9409x; 2.2596x over previous
//
#include <hip/hip_runtime.h>
#include <stdint.h>

typedef unsigned short u16;
typedef unsigned int   u32;

#define DEVINL __device__ __forceinline__

typedef __bf16 bf16x8 __attribute__((ext_vector_type(8)));
typedef float  f32x4  __attribute__((ext_vector_type(4)));

#define RSQRT512 0.044194173824159216f
#define LRELU_G  1.4142135623730951f

DEVINL u16 f2bf(float f) {           // RNE float->bf16 bits
  union { float f; u32 u; } v; v.f = f;
  u32 r = v.u + 0x7fffu + ((v.u >> 16) & 1u);
  return (u16)(r >> 16);
}
DEVINL float bf2f(u16 b) {
  union { u32 u; float f; } v; v.u = ((u32)b) << 16;
  return v.f;
}

// ---------------------------------------------------------------------------
// 1) styles: s_all[j][b][o] = ws[b,j,:]@A_j[o,:]/sqrt(512) + ab_j[o]; j==2 *= 1/sqrt(512)
// ---------------------------------------------------------------------------
__global__ __launch_bounds__(256)
void style_kernel(const float* __restrict__ wsin,
                  const float* __restrict__ a0w, const float* __restrict__ a0b,
                  const float* __restrict__ a1w, const float* __restrict__ a1b,
                  const float* __restrict__ atw, const float* __restrict__ atb,
                  float* __restrict__ s_all)
{
  int wid = threadIdx.x >> 6, lane = threadIdx.x & 63;
  int idx = blockIdx.x * 4 + wid;            // [0, 3*8*512)
  int j = idx >> 12;
  int b = (idx >> 9) & 7;
  int o = idx & 511;
  const float* A  = (j == 0) ? a0w : ((j == 1) ? a1w : atw);
  const float* Ab = (j == 0) ? a0b : ((j == 1) ? a1b : atb);
  const float* wv = wsin + (b * 3 + j) * 512;
  float p = 0.f;
  #pragma unroll
  for (int m = 0; m < 512; m += 64) p += wv[m + lane] * A[(size_t)o * 512 + m + lane];
  #pragma unroll
  for (int s = 32; s; s >>= 1) p += __shfl_xor(p, s, 64);
  if (lane == 0) {
    float v = p * RSQRT512 + Ab[o];
    if (j == 2) v *= RSQRT512;
    s_all[idx] = v;
  }
}

// ---------------------------------------------------------------------------
// 2) weight prep: modulate + demod, emit bf16 [b][o][tap*512 + i]
//    FLIP=1: tap index is (2-ky)*3+(2-kx)   (conv0's spatially-flipped kernel)
// ---------------------------------------------------------------------------
template <int FLIP>
__global__ __launch_bounds__(256)
void wprep_kernel(const float* __restrict__ w, const float* __restrict__ s_j,
                  u16* __restrict__ wg)
{
  int b = blockIdx.x >> 9;
  int o = blockIdx.x & 511;
  __shared__ float s_sh[512];
  __shared__ float red[4];
  int t = threadIdx.x;
  s_sh[t]       = s_j[b * 512 + t];
  s_sh[t + 256] = s_j[b * 512 + t + 256];
  __syncthreads();
  float wv[2][9];
  float ssq = 0.f;
  #pragma unroll
  for (int hh = 0; hh < 2; ++hh) {
    int i = t + hh * 256;
    float si = s_sh[i];
    const float* wp = w + ((size_t)o * 512 + i) * 9;
    #pragma unroll
    for (int k = 0; k < 9; ++k) { float v = wp[k] * si; wv[hh][k] = v; ssq += v * v; }
  }
  #pragma unroll
  for (int s = 32; s; s >>= 1) ssq += __shfl_xor(ssq, s, 64);
  if ((t & 63) == 0) red[t >> 6] = ssq;
  __syncthreads();
  float d = red[0] + red[1] + red[2] + red[3];
  d = 1.0f / sqrtf(d + 1e-8f);
  u16* out = wg + ((size_t)(b * 512 + o)) * 4608;
  #pragma unroll
  for (int hh = 0; hh < 2; ++hh) {
    int i = t + hh * 256;
    #pragma unroll
    for (int ky = 0; ky < 3; ++ky)
      #pragma unroll
      for (int kx = 0; kx < 3; ++kx) {
        int tap = FLIP ? ((2 - ky) * 3 + (2 - kx)) : (ky * 3 + kx);
        out[tap * 512 + i] = f2bf(wv[hh][ky * 3 + kx] * d);
      }
  }
}

// ---------------------------------------------------------------------------
// 3) x (NCHW f32 32x32) -> xt (NHWC f32 [b][y][x][512]) via LDS transpose
// ---------------------------------------------------------------------------
__global__ __launch_bounds__(256)
void transpose_x(const float* __restrict__ x, float* __restrict__ xt)
{
  int b = blockIdx.x >> 5, y = blockIdx.x & 31;
  __shared__ __align__(16) float lds[32][260];
  int t = threadIdx.x;
  #pragma unroll 1
  for (int half = 0; half < 2; ++half) {
    for (int idx = t; idx < 8192; idx += 256) {
      int xq = idx & 31, i = idx >> 5;
      lds[xq][i] = x[(((size_t)(b * 512 + half * 256 + i)) << 10) + (y << 5) + xq];
    }
    __syncthreads();
    for (int idx = t; idx < 2048; idx += 256) {
      int xq = idx >> 6, i4 = idx & 63;
      float4 v = *(const float4*)&lds[xq][i4 * 4];
      *(float4*)&xt[((size_t)((b * 32 + y) * 32 + xq) << 9) + half * 256 + i4 * 4] = v;
    }
    __syncthreads();
  }
}

// ---------------------------------------------------------------------------
// 4) blur-upsample: xt f32 [b][32][32][512] -> xb bf16 [b][66][66][512]
//    upfirdn2d(up=2, pad 3/2, gain 4) per-dim taps (.75/.25)
// ---------------------------------------------------------------------------
__global__ __launch_bounds__(256)
void upblur_kernel(const float* __restrict__ xt, u16* __restrict__ xb)
{
  int b = blockIdx.x / 66, p = blockIdx.x - b * 66;
  int t = threadIdx.x;
  int ch = t << 1;
  int m0, m1; float wy0, wy1;
  if ((p & 1) == 0) { m0 = (p >> 1) - 1; wy0 = 0.75f; m1 = p >> 1;       wy1 = 0.25f; }
  else              { m0 = (p - 3) >> 1; wy0 = 0.25f; m1 = (p - 1) >> 1; wy1 = 0.75f; }
  bool vm0 = (unsigned)m0 < 32u, vm1 = (unsigned)m1 < 32u;
  const float* base = xt + (size_t)b * 524288;            // b*32*32*512
  u16* ob = xb + ((size_t)(b * 66 + p)) * 66 * 512;
  for (int q = 0; q < 66; ++q) {
    int n0, n1; float wx0, wx1;
    if ((q & 1) == 0) { n0 = (q >> 1) - 1; wx0 = 0.75f; n1 = q >> 1;       wx1 = 0.25f; }
    else              { n0 = (q - 3) >> 1; wx0 = 0.25f; n1 = (q - 1) >> 1; wx1 = 0.75f; }
    bool vn0 = (unsigned)n0 < 32u, vn1 = (unsigned)n1 < 32u;
    float a0 = 0.f, a1 = 0.f;
    if (vm0 & vn0) { float2 u = *(const float2*)(base + (((size_t)m0 * 32 + n0) << 9) + ch);
                     float w = wy0 * wx0; a0 += w * u.x; a1 += w * u.y; }
    if (vm0 & vn1) { float2 u = *(const float2*)(base + (((size_t)m0 * 32 + n1) << 9) + ch);
                     float w = wy0 * wx1; a0 += w * u.x; a1 += w * u.y; }
    if (vm1 & vn0) { float2 u = *(const float2*)(base + (((size_t)m1 * 32 + n0) << 9) + ch);
                     float w = wy1 * wx0; a0 += w * u.x; a1 += w * u.y; }
    if (vm1 & vn1) { float2 u = *(const float2*)(base + (((size_t)m1 * 32 + n1) << 9) + ch);
                     float w = wy1 * wx1; a0 += w * u.x; a1 += w * u.y; }
    u32 outv = (u32)f2bf(a0) | ((u32)f2bf(a1) << 16);
    *(u32*)(ob + (q << 9) + ch) = outv;
  }
}

// ---------------------------------------------------------------------------
// 5) LDS-tiled MFMA conv, rebuilt from the GREEN round-6 kernel.
//    128o x 128px tile, 4 waves (wm=px-half, wn=o-half), BK=64.
//    LDS: padded rows [128][72] u16 (144B stride, ~2-way conflicts, NO swizzle).
//    Staging: global -> reg -> ds_write_b128 (linear row/chunk map, no swizzle).
//    Fragment math identical to verified round-6 kernel.
//    EPI=0 (conv0): A=pixels -> D[px][o], out hp NHWC bf16 (padded ring +1)
//    EPI=1 (conv1): A=weights -> D[o][px], out h NCHW f32 (d_out)
// ---------------------------------------------------------------------------
template <int EPI>
__global__ __launch_bounds__(256, 3)
void conv_tile(const u16* __restrict__ xin,   // [b][66][66][512] bf16
               const u16* __restrict__ wg,    // [b][512][4608]   bf16
               const float* __restrict__ noise,  // [64*64]
               const float* __restrict__ nsp,    // scalar
               const float* __restrict__ bias,   // [512]
               u16* __restrict__ hpOut,          // EPI=0 dest
               float* __restrict__ hOut)         // EPI=1 dest
{
  int blk = blockIdx.x;
  int b  = blk >> 7;
  int ot = (blk >> 5) & 3;
  int pt = blk & 31;
  int o0 = ot << 7;
  int y0 = pt << 1;

  __shared__ __align__(16) u16 ldsW[128][72];   // 144B row stride (padded)
  __shared__ __align__(16) u16 ldsX[128][72];

  int t = threadIdx.x;
  int wid = t >> 6;
  int lane = t & 63;
  int gq = lane >> 4, r = lane & 15;
  int wm = wid >> 1, wn = wid & 1;

  f32x4 acc[4][4];
  #pragma unroll
  for (int i = 0; i < 4; ++i)
    #pragma unroll
    for (int j = 0; j < 4; ++j) acc[i][j] = (f32x4){0.f, 0.f, 0.f, 0.f};

  const u16* wbase = wg + ((size_t)b * 512 + o0) * 4608;
  const u16* xbase = xin + (size_t)b * (66 * 66 * 512);

  #pragma unroll 1
  for (int chunk = 0; chunk < 72; ++chunk) {
    int tap = chunk >> 3;
    int c0  = (chunk & 7) << 6;
    int dy = (tap * 171) >> 9;       // tap/3 for tap in [0,9)
    int dx = tap - dy * 3;
    // ---- load to regs (global): 128 rows x 64 ch, linear (row, cc) map
    bf16x8 wreg[4], xreg[4];
    #pragma unroll
    for (int q = 0; q < 4; ++q) {
      int s = q * 256 + t;
      int row = s >> 3, cc = s & 7;
      wreg[q] = *(const bf16x8*)(wbase + (size_t)row * 4608 + tap * 512 + c0 + (cc << 3));
      int yy = y0 + (row >> 6) + dy;
      int xx = (row & 63) + dx;
      xreg[q] = *(const bf16x8*)(xbase + (((size_t)yy * 66 + xx) << 9) + c0 + (cc << 3));
    }
    __syncthreads();   // all waves done reading LDS of previous chunk
    #pragma unroll
    for (int q = 0; q < 4; ++q) {
      int s = q * 256 + t;
      int row = s >> 3, cc = s & 7;
      *(bf16x8*)&ldsW[row][cc << 3] = wreg[q];
      *(bf16x8*)&ldsX[row][cc << 3] = xreg[q];
    }
    __syncthreads();   // LDS visible
    const u16* Abase = (EPI == 0) ? &ldsX[0][0] : &ldsW[0][0];
    const u16* Bbase = (EPI == 0) ? &ldsW[0][0] : &ldsX[0][0];
    #pragma unroll
    for (int kk = 0; kk < 2; ++kk) {
      bf16x8 af[4], bfv[4];
      #pragma unroll
      for (int f = 0; f < 4; ++f) {
        int rowA = wm * 64 + f * 16 + r;
        af[f] = *(const bf16x8*)&Abase[rowA * 72 + ((kk * 4 + gq) << 3)];
        int rowB = wn * 64 + f * 16 + r;
        bfv[f] = *(const bf16x8*)&Bbase[rowB * 72 + ((kk * 4 + gq) << 3)];
      }
      #pragma unroll
      for (int fa = 0; fa < 4; ++fa)
        #pragma unroll
        for (int fb = 0; fb < 4; ++fb)
          acc[fa][fb] = __builtin_amdgcn_mfma_f32_16x16x32_bf16(af[fa], bfv[fb], acc[fa][fb], 0, 0, 0);
    }
  }

  float ns = nsp[0];
  // C/D map (HW-verified): col = lane&15 (B-index), row = (lane>>4)*4 + v (A-index)
  if constexpr (EPI == 0) {
    // A = pixels (wm half): px_in_frag = gq*4+v ; B = weights (wn half): o_in_frag = r
    #pragma unroll
    for (int fa = 0; fa < 4; ++fa) {
      #pragma unroll
      for (int fb = 0; fb < 4; ++fb) {
        int oo = o0 + wn * 64 + fb * 16 + r;
        float bo = bias[oo];
        #pragma unroll
        for (int v = 0; v < 4; ++v) {
          int p  = wm * 64 + fa * 16 + gq * 4 + v;
          int pg = (pt << 7) + p;
          int y = pg >> 6, x2 = pg & 63;
          float val = acc[fa][fb][v] + noise[pg] * ns + bo;
          val = (val >= 0.f ? val : 0.2f * val) * LRELU_G;
          val = fminf(fmaxf(val, -256.f), 256.f);
          hpOut[((size_t)b * 4356 + (size_t)(y + 1) * 66 + (x2 + 1)) * 512 + oo] = f2bf(val);
        }
      }
    }
  } else {
    // A = weights (wm half): o_in_frag = gq*4+v ; B = pixels (wn half): px_in_frag = r
    #pragma unroll
    for (int fa = 0; fa < 4; ++fa) {
      #pragma unroll
      for (int fb = 0; fb < 4; ++fb) {
        int p  = wn * 64 + fb * 16 + r;
        int pg = (pt << 7) + p;
        float nv = noise[pg] * ns;
        #pragma unroll
        for (int v = 0; v < 4; ++v) {
          int oo = o0 + wm * 64 + fa * 16 + gq * 4 + v;
          float val = acc[fa][fb][v] + nv + bias[oo];
          val = (val >= 0.f ? val : 0.2f * val) * LRELU_G;
          val = fminf(fmaxf(val, -256.f), 256.f);
          hOut[((size_t)(b * 512 + oo) << 12) + pg] = val;
        }
      }
    }
  }
}

// ---------------------------------------------------------------------------
// 6) toRGB + img skip: out2 = img_up + clip(sum_i h*st*wt + bt, +-256)
// ---------------------------------------------------------------------------
__global__ __launch_bounds__(256)
void torgb_kernel(const float* __restrict__ h, const float* __restrict__ s_all,
                  const float* __restrict__ wt, const float* __restrict__ bt,
                  const float* __restrict__ img, float* __restrict__ out2)
{
  int b = blockIdx.x >> 4;
  int y = ((blockIdx.x & 15) << 2) + (threadIdx.x >> 6);
  int x = threadIdx.x & 63;
  __shared__ float stw[3][512];
  const float* st = s_all + 2 * 4096 + b * 512;
  for (int i = threadIdx.x; i < 512; i += 256) {
    float s = st[i];
    stw[0][i] = s * wt[i];
    stw[1][i] = s * wt[512 + i];
    stw[2][i] = s * wt[1024 + i];
  }
  __syncthreads();
  const float* hp = h + ((size_t)b * 512 << 12) + (y << 6) + x;
  float a0 = 0.f, a1 = 0.f, a2 = 0.f;
  #pragma unroll 8
  for (int i = 0; i < 512; ++i) {
    float v = hp[(size_t)i << 12];
    a0 += v * stw[0][i]; a1 += v * stw[1][i]; a2 += v * stw[2][i];
  }
  float accs[3] = {a0, a1, a2};
  // img upfirdn (up=2, pad 2/1, gain 4): per-dim taps
  int my0, my1; float wy0, wy1;
  if ((y & 1) == 0) { my0 = (y >> 1) - 1; wy0 = 0.25f; my1 = y >> 1;       wy1 = 0.75f; }
  else              { my0 = y >> 1;       wy0 = 0.75f; my1 = (y >> 1) + 1; wy1 = 0.25f; }
  int mx0, mx1; float wx0, wx1;
  if ((x & 1) == 0) { mx0 = (x >> 1) - 1; wx0 = 0.25f; mx1 = x >> 1;       wx1 = 0.75f; }
  else              { mx0 = x >> 1;       wx0 = 0.75f; mx1 = (x >> 1) + 1; wx1 = 0.25f; }
  bool vy0 = (unsigned)my0 < 32u, vy1 = (unsigned)my1 < 32u;
  bool vx0 = (unsigned)mx0 < 32u, vx1 = (unsigned)mx1 < 32u;
  #pragma unroll
  for (int o = 0; o < 3; ++o) {
    float yv = fminf(fmaxf(accs[o] + bt[o], -256.f), 256.f);
    const float* ib = img + ((size_t)(b * 3 + o) << 10);
    float iu = 0.f;
    if (vy0 & vx0) iu += wy0 * wx0 * ib[(my0 << 5) + mx0];
    if (vy0 & vx1) iu += wy0 * wx1 * ib[(my0 << 5) + mx1];
    if (vy1 & vx0) iu += wy1 * wx0 * ib[(my1 << 5) + mx0];
    if (vy1 & vx1) iu += wy1 * wx1 * ib[(my1 << 5) + mx1];
    out2[((size_t)(b * 3 + o) << 12) + (y << 6) + x] = iu + yv;
  }
}

// ---------------------------------------------------------------------------
extern "C" void kernel_launch(void* const* d_in, const int* in_sizes, int n_in,
                              void* d_out, int out_size, void* d_ws, size_t ws_size,
                              hipStream_t stream) {
  (void)in_sizes; (void)n_in; (void)out_size; (void)ws_size;
  const float* x   = (const float*)d_in[0];
  const float* img = (const float*)d_in[1];
  const float* ws_ = (const float*)d_in[2];
  const float* a0w = (const float*)d_in[3];
  const float* a0b = (const float*)d_in[4];
  const float* w0  = (const float*)d_in[5];
  const float* b0  = (const float*)d_in[6];
  const float* ns0 = (const float*)d_in[7];
  const float* nc0 = (const float*)d_in[8];
  const float* a1w = (const float*)d_in[9];
  const float* a1b = (const float*)d_in[10];
  const float* w1  = (const float*)d_in[11];
  const float* b1  = (const float*)d_in[12];
  const float* ns1 = (const float*)d_in[13];
  const float* nc1 = (const float*)d_in[14];
  const float* atw = (const float*)d_in[15];
  const float* atb = (const float*)d_in[16];
  const float* wt  = (const float*)d_in[17];
  const float* bt  = (const float*)d_in[18];

  // workspace carve (total ~146.9 MB), all offsets 16B-aligned
  char* wsp = (char*)d_ws;
  float* s_all = (float*)wsp;                                   //      49,152 B
  u16* wg0 = (u16*)(wsp + 49152);                               //  37,748,736 B
  u16* wg1 = (u16*)(wsp + 49152 + 37748736ull);                 //  37,748,736 B
  u16* xb  = (u16*)(wsp + 49152 + 2ull * 37748736);             //  35,684,352 B
  u16* hp  = (u16*)(wsp + 49152 + 2ull * 37748736 + 35684352);  //  35,684,352 B
  float* xtf = (float*)hp;   // xt f32 (16,777,216 B) aliases hp; dead before memset

  float* h_out = (float*)d_out;
  float* out2  = (float*)d_out + 16777216;

  style_kernel<<<3072, 256, 0, stream>>>(ws_, a0w, a0b, a1w, a1b, atw, atb, s_all);
  wprep_kernel<1><<<4096, 256, 0, stream>>>(w0, s_all, wg0);           // conv0: flipped
  wprep_kernel<0><<<4096, 256, 0, stream>>>(w1, s_all + 4096, wg1);    // conv1
  transpose_x<<<256, 256, 0, stream>>>(x, xtf);
  upblur_kernel<<<528, 256, 0, stream>>>(xtf, xb);
  hipMemsetAsync(hp, 0, 35684352, stream);  // zero padded ring for conv1 input (xtf now dead)
  conv_tile<0><<<1024, 256, 0, stream>>>(xb, wg0, nc0, ns0, b0, hp, nullptr);
  conv_tile<1><<<1024, 256, 0, stream>>>(hp, wg1, nc1, ns1, b1, nullptr, h_out);
  torgb_kernel<<<128, 256, 0, stream>>>(h_out, s_all, wt, bt, img, out2);
}